// Round 2
// baseline (1960.134 us; speedup 1.0000x reference)
//
#include <hip/hip_runtime.h>
#include <math.h>

#define N_NODES 100000
#define N_EDGES 6400000
#define D_IN 512
#define D_HID 16

// ---- bucketed counting-sort parameters ----
#define BSHIFT 7
#define BNODES 128                                   // nodes per bucket
#define NB ((N_NODES + BNODES - 1) / BNODES)         // 782 buckets
#define P2_TILE 8192                                 // edges per block in p1/p2
#define NTILES ((N_EDGES + P2_TILE - 1) / P2_TILE)   // 782
#define CAP 9728                                     // max edges/bucket (mean 8184 + ~17 sigma)
#define SBINS 1024                                   // src-sort bins (src>>7 -> 782 used)

// ---------------- pass 1: bucket histogram ----------------
__global__ __launch_bounds__(256) void p1_hist(const int* __restrict__ dst,
                                               int* __restrict__ bcnt) {
    __shared__ int h[NB];
    int tid = threadIdx.x;
    for (int i = tid; i < NB; i += 256) h[i] = 0;
    __syncthreads();
    int base = blockIdx.x * P2_TILE;
#pragma unroll
    for (int k = 0; k < P2_TILE / 256; k++) {
        int e = base + k * 256 + tid;
        if (e < N_EDGES) atomicAdd(&h[dst[e] >> BSHIFT], 1);
    }
    __syncthreads();
    for (int i = tid; i < NB; i += 256) {
        int c = h[i];
        if (c) atomicAdd(&bcnt[i], c);
    }
}

// ---------------- pass 2a: scan bucket counts (1 block) ----------------
__global__ void p2_scan(const int* __restrict__ bcnt, int* __restrict__ bstart,
                        int* __restrict__ bcur) {
    __shared__ int sd[1024];
    int tid = threadIdx.x;  // 1024 threads
    int v = (tid < NB) ? bcnt[tid] : 0;
    sd[tid] = v;
    __syncthreads();
    for (int off = 1; off < 1024; off <<= 1) {
        int u = (tid >= off) ? sd[tid - off] : 0;
        __syncthreads();
        sd[tid] += u;
        __syncthreads();
    }
    if (tid < NB) {
        int ex = sd[tid] - v;
        bstart[tid] = ex;
        bcur[tid] = ex;
    }
}

// ---------------- pass 2b: aggregated multisplit scatter ----------------
__global__ __launch_bounds__(256) void p2_scatter(const int* __restrict__ src,
                                                  const int* __restrict__ dst,
                                                  int* __restrict__ bcur,
                                                  unsigned int* __restrict__ staged) {
    __shared__ int h[NB];
    int tid = threadIdx.x;
    for (int i = tid; i < NB; i += 256) h[i] = 0;
    __syncthreads();
    int base = blockIdx.x * P2_TILE;
#pragma unroll
    for (int k = 0; k < P2_TILE / 256; k++) {
        int e = base + k * 256 + tid;
        if (e < N_EDGES) atomicAdd(&h[dst[e] >> BSHIFT], 1);
    }
    __syncthreads();
    for (int i = tid; i < NB; i += 256) {
        int c = h[i];
        h[i] = c ? atomicAdd(&bcur[i], c) : 0;
    }
    __syncthreads();
#pragma unroll
    for (int k = 0; k < P2_TILE / 256; k++) {
        int e = base + k * 256 + tid;
        if (e < N_EDGES) {
            int d = dst[e];
            int b = d >> BSHIFT;
            int pos = atomicAdd(&h[b], 1);
            staged[pos] = ((unsigned int)src[e] << BSHIFT) | (unsigned int)(d & (BNODES - 1));
        }
    }
}

// ---------------- pass 3: per-bucket src-sort + dinv ----------------
// One block per bucket. Sort the bucket's packed edges by src-bin (src>>7)
// so aggregation gathers sweep the feature table coherently. Also derive
// per-node degree -> dinv. Edges stay packed (src<<7 | local_dst).
__global__ __launch_bounds__(256) void p3_build(unsigned int* __restrict__ ebuf,
                                                const int* __restrict__ bstart,
                                                const int* __restrict__ bcnt,
                                                float* __restrict__ dinv) {
    __shared__ unsigned int buf[CAP];
    __shared__ int bins[SBINS];
    __shared__ int dcnt[BNODES];
    __shared__ int sd[256];
    int b = blockIdx.x;
    int tid = threadIdx.x;
    int ebase = bstart[b];
    int ecnt = bcnt[b];
    if (ecnt > CAP) ecnt = CAP;  // statistically impossible; guards LDS
    for (int i = tid; i < SBINS; i += 256) bins[i] = 0;
    if (tid < BNODES) dcnt[tid] = 0;
    __syncthreads();
    for (int i = tid; i < ecnt; i += 256) {
        unsigned int e = ebuf[ebase + i];
        buf[i] = e;
        atomicAdd(&bins[e >> (BSHIFT + 7)], 1);   // src>>7
        atomicAdd(&dcnt[e & (BNODES - 1)], 1);
    }
    __syncthreads();
    // dinv
    int node = b * BNODES + tid;
    if (tid < BNODES && node < N_NODES)
        dinv[node] = rsqrtf((float)dcnt[tid] + 1.0f);  // +1 self-loop
    // exclusive scan over bins[1024]: 4 per thread + block scan
    int t4 = tid * 4;
    int c0 = bins[t4], c1 = bins[t4 + 1], c2 = bins[t4 + 2], c3 = bins[t4 + 3];
    int ts = c0 + c1 + c2 + c3;
    sd[tid] = ts;
    __syncthreads();
    for (int off = 1; off < 256; off <<= 1) {
        int u = (tid >= off) ? sd[tid - off] : 0;
        __syncthreads();
        sd[tid] += u;
        __syncthreads();
    }
    int texcl = sd[tid] - ts;
    __syncthreads();
    bins[t4]     = texcl;
    bins[t4 + 1] = texcl + c0;
    bins[t4 + 2] = texcl + c0 + c1;
    bins[t4 + 3] = texcl + c0 + c1 + c2;
    __syncthreads();
    // scatter sorted by src-bin
    for (int i = tid; i < ecnt; i += 256) {
        unsigned int e = buf[i];
        int pos = atomicAdd(&bins[e >> (BSHIFT + 7)], 1);
        ebuf[ebase + pos] = e;
    }
}

// ---------------- GEMM1: hs1 = (x @ W1) * dinv[row] ----------------
__global__ __launch_bounds__(256) void gemm1(const float* __restrict__ x,
                                             const float* __restrict__ W1,
                                             const float* __restrict__ dinv,
                                             float* __restrict__ hs1) {
    __shared__ float xs[256 * 33];
    int tid = threadIdx.x;
    int row0 = blockIdx.x * 256;
    int row = row0 + tid;
    float acc[16];
#pragma unroll
    for (int c = 0; c < 16; c++) acc[c] = 0.f;

    for (int k0 = 0; k0 < D_IN; k0 += 32) {
        __syncthreads();
#pragma unroll
        for (int l = 0; l < 8; l++) {
            int idx = tid + l * 256;   // 0..2047
            int r = idx >> 3;
            int f4 = idx & 7;
            int gr = row0 + r;
            float4 v = make_float4(0.f, 0.f, 0.f, 0.f);
            if (gr < N_NODES)
                v = *(const float4*)(x + (size_t)gr * D_IN + k0 + f4 * 4);
            int a = r * 33 + f4 * 4;
            xs[a] = v.x; xs[a + 1] = v.y; xs[a + 2] = v.z; xs[a + 3] = v.w;
        }
        __syncthreads();
#pragma unroll
        for (int kk = 0; kk < 32; kk++) {
            float xv = xs[tid * 33 + kk];
            const float* wr = W1 + (k0 + kk) * 16;  // wave-uniform -> s_load
#pragma unroll
            for (int c = 0; c < 16; c++) acc[c] = fmaf(xv, wr[c], acc[c]);
        }
    }
    if (row < N_NODES) {
        float di = dinv[row];
        float4* o = (float4*)(hs1 + (size_t)row * 16);
        o[0] = make_float4(acc[0] * di, acc[1] * di, acc[2] * di, acc[3] * di);
        o[1] = make_float4(acc[4] * di, acc[5] * di, acc[6] * di, acc[7] * di);
        o[2] = make_float4(acc[8] * di, acc[9] * di, acc[10] * di, acc[11] * di);
        o[3] = make_float4(acc[12] * di, acc[13] * di, acc[14] * di, acc[15] * di);
    }
}

// ---------------- Agg layer 1: edge-parallel + bias + ReLU + @W2, store *dinv
__global__ __launch_bounds__(512) void agg1(const float* __restrict__ hs1,
                                            const float* __restrict__ dinv,
                                            const int* __restrict__ bstart,
                                            const int* __restrict__ bcnt,
                                            const unsigned int* __restrict__ ebuf,
                                            const float* __restrict__ b1,
                                            const float* __restrict__ W2,
                                            float* __restrict__ hs3) {
    __shared__ float acc[BNODES * 16];  // 8 KB
    __shared__ unsigned int eW[1024];   // 4 KB edge stage
    int b = blockIdx.x;
    int tid = threadIdx.x;
    int g = tid >> 4;       // group 0..31
    int c = tid & 15;       // feature lane
    for (int i = tid; i < BNODES * 16; i += 512) acc[i] = 0.f;
    int base = bstart[b];
    int cnt = bcnt[b];
    int nfull = cnt & ~1023;
    for (int t0 = 0; t0 < nfull; t0 += 1024) {
        __syncthreads();
        for (int i = tid; i < 1024; i += 512) eW[i] = ebuf[base + t0 + i];
        __syncthreads();
#pragma unroll 4
        for (int j = g; j < 1024; j += 32) {
            unsigned int e = eW[j];
            int s = e >> BSHIFT;
            int d = e & (BNODES - 1);
            float v = hs1[(size_t)s * 16 + c];
            unsafeAtomicAdd(&acc[d * 16 + c], v);
        }
    }
    {   // tail
        __syncthreads();
        int nld = cnt - nfull;
        for (int i = tid; i < nld; i += 512) eW[i] = ebuf[base + nfull + i];
        __syncthreads();
        for (int j = g; j < nld; j += 32) {
            unsigned int e = eW[j];
            int s = e >> BSHIFT;
            int d = e & (BNODES - 1);
            float v = hs1[(size_t)s * 16 + c];
            unsafeAtomicAdd(&acc[d * 16 + c], v);
        }
    }
    __syncthreads();
    // epilogue: 32 groups x 4 nodes
#pragma unroll
    for (int k = 0; k < 4; k++) {
        int ln = g + k * 32;
        int node = b * BNODES + ln;
        if (node < N_NODES) {
            float di = dinv[node];
            float a = acc[ln * 16 + c] + hs1[(size_t)node * 16 + c];  // + self
            float v = a * di + b1[c];
            v = v > 0.f ? v : 0.f;
            float outv = 0.f;
#pragma unroll
            for (int j = 0; j < 16; j++) {
                float vj = __shfl(v, j, 16);
                outv = fmaf(vj, W2[j * 16 + c], outv);
            }
            hs3[(size_t)node * 16 + c] = outv * di;
        }
    }
}

// ---------------- Agg layer 2: edge-parallel + b2 + log_softmax ----------------
__global__ __launch_bounds__(512) void agg2(const float* __restrict__ hs3,
                                            const float* __restrict__ dinv,
                                            const int* __restrict__ bstart,
                                            const int* __restrict__ bcnt,
                                            const unsigned int* __restrict__ ebuf,
                                            const float* __restrict__ b2,
                                            float* __restrict__ out) {
    __shared__ float acc[BNODES * 16];
    __shared__ unsigned int eW[1024];
    int b = blockIdx.x;
    int tid = threadIdx.x;
    int g = tid >> 4;
    int c = tid & 15;
    for (int i = tid; i < BNODES * 16; i += 512) acc[i] = 0.f;
    int base = bstart[b];
    int cnt = bcnt[b];
    int nfull = cnt & ~1023;
    for (int t0 = 0; t0 < nfull; t0 += 1024) {
        __syncthreads();
        for (int i = tid; i < 1024; i += 512) eW[i] = ebuf[base + t0 + i];
        __syncthreads();
#pragma unroll 4
        for (int j = g; j < 1024; j += 32) {
            unsigned int e = eW[j];
            int s = e >> BSHIFT;
            int d = e & (BNODES - 1);
            float v = hs3[(size_t)s * 16 + c];
            unsafeAtomicAdd(&acc[d * 16 + c], v);
        }
    }
    {   // tail
        __syncthreads();
        int nld = cnt - nfull;
        for (int i = tid; i < nld; i += 512) eW[i] = ebuf[base + nfull + i];
        __syncthreads();
        for (int j = g; j < nld; j += 32) {
            unsigned int e = eW[j];
            int s = e >> BSHIFT;
            int d = e & (BNODES - 1);
            float v = hs3[(size_t)s * 16 + c];
            unsafeAtomicAdd(&acc[d * 16 + c], v);
        }
    }
    __syncthreads();
#pragma unroll
    for (int k = 0; k < 4; k++) {
        int ln = g + k * 32;
        int node = b * BNODES + ln;
        if (node < N_NODES) {
            float di = dinv[node];
            float logit = (acc[ln * 16 + c] + hs3[(size_t)node * 16 + c]) * di + b2[c];
            float m = logit;
#pragma unroll
            for (int mask = 1; mask < 16; mask <<= 1)
                m = fmaxf(m, __shfl_xor(m, mask, 16));
            float e = expf(logit - m);
            float ssum = e;
#pragma unroll
            for (int mask = 1; mask < 16; mask <<= 1)
                ssum += __shfl_xor(ssum, mask, 16);
            out[(size_t)node * 16 + c] = (logit - m) - logf(ssum);
        }
    }
}

extern "C" void kernel_launch(void* const* d_in, const int* in_sizes, int n_in,
                              void* d_out, int out_size, void* d_ws, size_t ws_size,
                              hipStream_t stream) {
    const float* x  = (const float*)d_in[0];
    const float* W1 = (const float*)d_in[1];
    const float* b1 = (const float*)d_in[2];
    const float* W2 = (const float*)d_in[3];
    const float* b2 = (const float*)d_in[4];
    const int*   ei = (const int*)d_in[5];
    const int* src = ei;
    const int* dst = ei + N_EDGES;
    float* out = (float*)d_out;

    // workspace layout (elements, all 4B):
    float* dinv    = (float*)d_ws;                // 100096
    int* bcnt      = (int*)(dinv + 100096);       // 1024
    int* bstart    = bcnt + 1024;                 // 1024
    int* bcur      = bstart + 1024;               // 1024
    unsigned int* ebuf = (unsigned int*)(bcur + 1024); // 6400000 packed (src<<7|d)
    float* hs1     = (float*)(ebuf + N_EDGES);    // 1600000
    float* hs3     = hs1 + 1600000;               // 1600000

    hipMemsetAsync(bcnt, 0, NB * sizeof(int), stream);
    p1_hist<<<NTILES, 256, 0, stream>>>(dst, bcnt);
    p2_scan<<<1, 1024, 0, stream>>>(bcnt, bstart, bcur);
    p2_scatter<<<NTILES, 256, 0, stream>>>(src, dst, bcur, ebuf);
    p3_build<<<NB, 256, 0, stream>>>(ebuf, bstart, bcnt, dinv);
    gemm1<<<(N_NODES + 255) / 256, 256, 0, stream>>>(x, W1, dinv, hs1);
    agg1<<<NB, 512, 0, stream>>>(hs1, dinv, bstart, bcnt, ebuf, b1, W2, hs3);
    agg2<<<NB, 512, 0, stream>>>(hs3, dinv, bstart, bcnt, ebuf, b2, out);
}

// Round 3
// 881.716 us; speedup vs baseline: 2.2231x; 2.2231x over previous
//
#include <hip/hip_runtime.h>
#include <math.h>

#define N_NODES 100000
#define N_EDGES 6400000
#define D_IN 512
#define D_HID 16

// ---- bucketed counting-sort parameters ----
#define BSHIFT 7
#define BNODES 128                                   // nodes per bucket
#define NB ((N_NODES + BNODES - 1) / BNODES)         // 782 buckets
#define P2_TILE 8192                                 // edges per block in p1/p2
#define NTILES ((N_EDGES + P2_TILE - 1) / P2_TILE)   // 782
#define CAP 9728                                     // max edges/bucket (mean 8184 + ~17 sigma)

// ---------------- pass 1: bucket histogram ----------------
__global__ __launch_bounds__(256) void p1_hist(const int* __restrict__ dst,
                                               int* __restrict__ bcnt) {
    __shared__ int h[NB];
    int tid = threadIdx.x;
    for (int i = tid; i < NB; i += 256) h[i] = 0;
    __syncthreads();
    int base = blockIdx.x * P2_TILE;
#pragma unroll
    for (int k = 0; k < P2_TILE / 256; k++) {
        int e = base + k * 256 + tid;
        if (e < N_EDGES) atomicAdd(&h[dst[e] >> BSHIFT], 1);
    }
    __syncthreads();
    for (int i = tid; i < NB; i += 256) {
        int c = h[i];
        if (c) atomicAdd(&bcnt[i], c);
    }
}

// ---------------- pass 2a: scan bucket counts (1 block) ----------------
__global__ void p2_scan(const int* __restrict__ bcnt, int* __restrict__ bstart,
                        int* __restrict__ bcur) {
    __shared__ int sd[1024];
    int tid = threadIdx.x;  // 1024 threads
    int v = (tid < NB) ? bcnt[tid] : 0;
    sd[tid] = v;
    __syncthreads();
    for (int off = 1; off < 1024; off <<= 1) {
        int u = (tid >= off) ? sd[tid - off] : 0;
        __syncthreads();
        sd[tid] += u;
        __syncthreads();
    }
    if (tid < NB) {
        int ex = sd[tid] - v;
        bstart[tid] = ex;
        bcur[tid] = ex;
    }
}

// ---------------- pass 2b: aggregated multisplit scatter ----------------
__global__ __launch_bounds__(256) void p2_scatter(const int* __restrict__ src,
                                                  const int* __restrict__ dst,
                                                  int* __restrict__ bcur,
                                                  unsigned int* __restrict__ staged) {
    __shared__ int h[NB];
    int tid = threadIdx.x;
    for (int i = tid; i < NB; i += 256) h[i] = 0;
    __syncthreads();
    int base = blockIdx.x * P2_TILE;
#pragma unroll
    for (int k = 0; k < P2_TILE / 256; k++) {
        int e = base + k * 256 + tid;
        if (e < N_EDGES) atomicAdd(&h[dst[e] >> BSHIFT], 1);
    }
    __syncthreads();
    for (int i = tid; i < NB; i += 256) {
        int c = h[i];
        h[i] = c ? atomicAdd(&bcur[i], c) : 0;
    }
    __syncthreads();
#pragma unroll
    for (int k = 0; k < P2_TILE / 256; k++) {
        int e = base + k * 256 + tid;
        if (e < N_EDGES) {
            int d = dst[e];
            int b = d >> BSHIFT;
            int pos = atomicAdd(&h[b], 1);
            staged[pos] = ((unsigned int)src[e] << BSHIFT) | (unsigned int)(d & (BNODES - 1));
        }
    }
}

// ---------------- pass 3: per-bucket CSR build (+deg, row_start, dinv) ------
// One block per bucket: LDS counting sort by local dst; final CSR = plain src.
__global__ __launch_bounds__(256) void p3_build(unsigned int* __restrict__ ebuf,
                                                const int* __restrict__ bstart,
                                                const int* __restrict__ bcnt,
                                                int* __restrict__ row_start,
                                                int* __restrict__ deg,
                                                float* __restrict__ dinv) {
    __shared__ unsigned int buf[CAP];
    __shared__ int cnt[BNODES];
    __shared__ int cur[BNODES];
    int b = blockIdx.x;
    int tid = threadIdx.x;
    int ebase = bstart[b];
    int ecnt = bcnt[b];
    if (ecnt > CAP) ecnt = CAP;  // statistically impossible; guards LDS
    if (tid < BNODES) cnt[tid] = 0;
    __syncthreads();
    for (int i = tid; i < ecnt; i += 256) {
        unsigned int v = ebuf[ebase + i];
        buf[i] = v;
        atomicAdd(&cnt[v & (BNODES - 1)], 1);
    }
    __syncthreads();
    // exclusive scan over cnt[128]
    int c = 0;
    if (tid < BNODES) {
        c = cnt[tid];
        cur[tid] = c;
    }
    __syncthreads();
    for (int off = 1; off < BNODES; off <<= 1) {
        int u = 0;
        if (tid < BNODES && tid >= off) u = cur[tid - off];
        __syncthreads();
        if (tid < BNODES) cur[tid] += u;
        __syncthreads();
    }
    int excl = 0;
    if (tid < BNODES) excl = cur[tid] - c;
    int node = b * BNODES + tid;
    if (tid < BNODES && node < N_NODES) {
        row_start[node] = ebase + excl;
        deg[node] = c;
        dinv[node] = rsqrtf((float)c + 1.0f);  // +1 self-loop
    }
    __syncthreads();
    if (tid < BNODES) cur[tid] = excl;  // local cursor
    __syncthreads();
    for (int i = tid; i < ecnt; i += 256) {
        unsigned int v = buf[i];
        int pos = atomicAdd(&cur[v & (BNODES - 1)], 1);
        ebuf[ebase + pos] = v >> BSHIFT;  // final CSR: src id
    }
}

// ---------------- GEMM1: hs1 = (x @ W1) * dinv[row] ----------------
__global__ __launch_bounds__(256) void gemm1(const float* __restrict__ x,
                                             const float* __restrict__ W1,
                                             const float* __restrict__ dinv,
                                             float* __restrict__ hs1) {
    __shared__ float xs[256 * 33];
    int tid = threadIdx.x;
    int row0 = blockIdx.x * 256;
    int row = row0 + tid;
    float acc[16];
#pragma unroll
    for (int c = 0; c < 16; c++) acc[c] = 0.f;

    for (int k0 = 0; k0 < D_IN; k0 += 32) {
        __syncthreads();
#pragma unroll
        for (int l = 0; l < 8; l++) {
            int idx = tid + l * 256;   // 0..2047
            int r = idx >> 3;
            int f4 = idx & 7;
            int gr = row0 + r;
            float4 v = make_float4(0.f, 0.f, 0.f, 0.f);
            if (gr < N_NODES)
                v = *(const float4*)(x + (size_t)gr * D_IN + k0 + f4 * 4);
            int a = r * 33 + f4 * 4;
            xs[a] = v.x; xs[a + 1] = v.y; xs[a + 2] = v.z; xs[a + 3] = v.w;
        }
        __syncthreads();
#pragma unroll
        for (int kk = 0; kk < 32; kk++) {
            float xv = xs[tid * 33 + kk];
            const float* wr = W1 + (k0 + kk) * 16;  // wave-uniform -> s_load
#pragma unroll
            for (int c = 0; c < 16; c++) acc[c] = fmaf(xv, wr[c], acc[c]);
        }
    }
    if (row < N_NODES) {
        float di = dinv[row];
        float4* o = (float4*)(hs1 + (size_t)row * 16);
        o[0] = make_float4(acc[0] * di, acc[1] * di, acc[2] * di, acc[3] * di);
        o[1] = make_float4(acc[4] * di, acc[5] * di, acc[6] * di, acc[7] * di);
        o[2] = make_float4(acc[8] * di, acc[9] * di, acc[10] * di, acc[11] * di);
        o[3] = make_float4(acc[12] * di, acc[13] * di, acc[14] * di, acc[15] * di);
    }
}

// ---------------- Agg layer 1: wave-per-node pull, 4 edge slots ----------------
// out_node = di * (sum_s hs1[s] + hs1[node]); then bias+ReLU+@W2, store *di.
__global__ __launch_bounds__(256) void agg1(const float* __restrict__ hs1,
                                            const float* __restrict__ dinv,
                                            const int* __restrict__ row_start,
                                            const int* __restrict__ deg,
                                            const int* __restrict__ csr,
                                            const float* __restrict__ b1,
                                            const float* __restrict__ W2,
                                            float* __restrict__ hs3) {
    int tid = threadIdx.x;
    int node = blockIdx.x * 4 + (tid >> 6);
    if (node >= N_NODES) return;
    int lane = tid & 63;
    int slot = lane >> 4;
    int c = lane & 15;
    int start = row_start[node];
    int cnt = deg[node];
    float acc = 0.f;
    // distance-2 software pipeline over this slot's edges (t = slot, slot+4, ...)
    float v0 = 0.f, v1 = 0.f;
    int t = slot;
    {
        int sA = (t < cnt) ? csr[start + t] : 0;
        int sB = (t + 4 < cnt) ? csr[start + t + 4] : 0;
        if (t < cnt) v0 = hs1[(size_t)sA * 16 + c];
        if (t + 4 < cnt) v1 = hs1[(size_t)sB * 16 + c];
    }
    for (; t < cnt; t += 4) {
        float vC = v0;
        v0 = v1;
        int tn = t + 8;
        if (tn < cnt) {
            int s = csr[start + tn];
            v1 = hs1[(size_t)s * 16 + c];
        } else {
            v1 = 0.f;
        }
        acc += vC;
    }
    // reduce across 4 slots
    acc += __shfl_xor(acc, 16);
    acc += __shfl_xor(acc, 32);
    float di = dinv[node];
    float v = (acc + hs1[(size_t)node * 16 + c]) * di + b1[c];
    v = v > 0.f ? v : 0.f;
    float outv = 0.f;
#pragma unroll
    for (int j = 0; j < 16; j++) {
        float vj = __shfl(v, j, 16);
        outv = fmaf(vj, W2[j * 16 + c], outv);
    }
    if (slot == 0) hs3[(size_t)node * 16 + c] = outv * di;
}

// ---------------- Agg layer 2: wave-per-node pull + b2 + log_softmax --------
__global__ __launch_bounds__(256) void agg2(const float* __restrict__ hs3,
                                            const float* __restrict__ dinv,
                                            const int* __restrict__ row_start,
                                            const int* __restrict__ deg,
                                            const int* __restrict__ csr,
                                            const float* __restrict__ b2,
                                            float* __restrict__ out) {
    int tid = threadIdx.x;
    int node = blockIdx.x * 4 + (tid >> 6);
    if (node >= N_NODES) return;
    int lane = tid & 63;
    int slot = lane >> 4;
    int c = lane & 15;
    int start = row_start[node];
    int cnt = deg[node];
    float acc = 0.f;
    float v0 = 0.f, v1 = 0.f;
    int t = slot;
    {
        int sA = (t < cnt) ? csr[start + t] : 0;
        int sB = (t + 4 < cnt) ? csr[start + t + 4] : 0;
        if (t < cnt) v0 = hs3[(size_t)sA * 16 + c];
        if (t + 4 < cnt) v1 = hs3[(size_t)sB * 16 + c];
    }
    for (; t < cnt; t += 4) {
        float vC = v0;
        v0 = v1;
        int tn = t + 8;
        if (tn < cnt) {
            int s = csr[start + tn];
            v1 = hs3[(size_t)s * 16 + c];
        } else {
            v1 = 0.f;
        }
        acc += vC;
    }
    acc += __shfl_xor(acc, 16);
    acc += __shfl_xor(acc, 32);
    float di = dinv[node];
    float logit = (acc + hs3[(size_t)node * 16 + c]) * di + b2[c];
    // log_softmax over 16 feature lanes (values identical across slots)
    float m = logit;
#pragma unroll
    for (int mask = 1; mask < 16; mask <<= 1)
        m = fmaxf(m, __shfl_xor(m, mask, 16));
    float e = expf(logit - m);
    float ssum = e;
#pragma unroll
    for (int mask = 1; mask < 16; mask <<= 1)
        ssum += __shfl_xor(ssum, mask, 16);
    if (slot == 0) out[(size_t)node * 16 + c] = (logit - m) - logf(ssum);
}

extern "C" void kernel_launch(void* const* d_in, const int* in_sizes, int n_in,
                              void* d_out, int out_size, void* d_ws, size_t ws_size,
                              hipStream_t stream) {
    const float* x  = (const float*)d_in[0];
    const float* W1 = (const float*)d_in[1];
    const float* b1 = (const float*)d_in[2];
    const float* W2 = (const float*)d_in[3];
    const float* b2 = (const float*)d_in[4];
    const int*   ei = (const int*)d_in[5];
    const int* src = ei;
    const int* dst = ei + N_EDGES;
    float* out = (float*)d_out;

    // workspace layout (elements, all 4B):
    int* deg       = (int*)d_ws;                  // 100096
    int* row_start = deg + 100096;                // 100096
    float* dinv    = (float*)(row_start + 100096);// 100096
    int* bcnt      = (int*)(dinv + 100096);       // 1024
    int* bstart    = bcnt + 1024;                 // 1024
    int* bcur      = bstart + 1024;               // 1024
    unsigned int* ebuf = (unsigned int*)(bcur + 1024); // 6400000
    float* hs1     = (float*)(ebuf + N_EDGES);    // 1600000
    float* hs3     = hs1 + 1600000;               // 1600000

    hipMemsetAsync(bcnt, 0, NB * sizeof(int), stream);
    p1_hist<<<NTILES, 256, 0, stream>>>(dst, bcnt);
    p2_scan<<<1, 1024, 0, stream>>>(bcnt, bstart, bcur);
    p2_scatter<<<NTILES, 256, 0, stream>>>(src, dst, bcur, ebuf);
    p3_build<<<NB, 256, 0, stream>>>(ebuf, bstart, bcnt, row_start, deg, dinv);
    gemm1<<<(N_NODES + 255) / 256, 256, 0, stream>>>(x, W1, dinv, hs1);
    agg1<<<(N_NODES + 3) / 4, 256, 0, stream>>>(hs1, dinv, row_start, deg, (const int*)ebuf, b1, W2, hs3);
    agg2<<<(N_NODES + 3) / 4, 256, 0, stream>>>(hs3, dinv, row_start, deg, (const int*)ebuf, b2, out);
}

// Round 4
// 758.957 us; speedup vs baseline: 2.5827x; 1.1617x over previous
//
#include <hip/hip_runtime.h>
#include <hip/hip_fp16.h>
#include <math.h>

#define N_NODES 100000
#define N_EDGES 6400000
#define D_IN 512
#define D_HID 16

// ---- bucketed counting-sort parameters ----
#define BSHIFT 7
#define BNODES 128                                   // nodes per bucket
#define NB ((N_NODES + BNODES - 1) / BNODES)         // 782 buckets
#define P1_TILE 8192
#define NT1 ((N_EDGES + P1_TILE - 1) / P1_TILE)      // 782
#define P2_TILE 25600                                // bigger tile -> longer runs, less write amp
#define NT2 (N_EDGES / P2_TILE)                      // 250
#define CAP 9728                                     // max edges/bucket (mean 8184 + ~17 sigma)

// ---------------- pass 1: bucket histogram ----------------
__global__ __launch_bounds__(256) void p1_hist(const int* __restrict__ dst,
                                               int* __restrict__ bcnt) {
    __shared__ int h[NB];
    int tid = threadIdx.x;
    for (int i = tid; i < NB; i += 256) h[i] = 0;
    __syncthreads();
    int base = blockIdx.x * P1_TILE;
#pragma unroll
    for (int k = 0; k < P1_TILE / 256; k++) {
        int e = base + k * 256 + tid;
        if (e < N_EDGES) atomicAdd(&h[dst[e] >> BSHIFT], 1);
    }
    __syncthreads();
    for (int i = tid; i < NB; i += 256) {
        int c = h[i];
        if (c) atomicAdd(&bcnt[i], c);
    }
}

// ---------------- pass 2a: scan bucket counts (1 block) ----------------
__global__ void p2_scan(const int* __restrict__ bcnt, int* __restrict__ bstart,
                        int* __restrict__ bcur) {
    __shared__ int sd[1024];
    int tid = threadIdx.x;  // 1024 threads
    int v = (tid < NB) ? bcnt[tid] : 0;
    sd[tid] = v;
    __syncthreads();
    for (int off = 1; off < 1024; off <<= 1) {
        int u = (tid >= off) ? sd[tid - off] : 0;
        __syncthreads();
        sd[tid] += u;
        __syncthreads();
    }
    if (tid < NB) {
        int ex = sd[tid] - v;
        bstart[tid] = ex;
        bcur[tid] = ex;
    }
}

// ---------------- pass 2b: aggregated multisplit scatter ----------------
__global__ __launch_bounds__(256) void p2_scatter(const int* __restrict__ src,
                                                  const int* __restrict__ dst,
                                                  int* __restrict__ bcur,
                                                  unsigned int* __restrict__ staged) {
    __shared__ int h[NB];
    int tid = threadIdx.x;
    for (int i = tid; i < NB; i += 256) h[i] = 0;
    __syncthreads();
    int base = blockIdx.x * P2_TILE;
    for (int k = 0; k < P2_TILE / 256; k++) {
        int e = base + k * 256 + tid;
        if (e < N_EDGES) atomicAdd(&h[dst[e] >> BSHIFT], 1);
    }
    __syncthreads();
    for (int i = tid; i < NB; i += 256) {
        int c = h[i];
        h[i] = c ? atomicAdd(&bcur[i], c) : 0;
    }
    __syncthreads();
    for (int k = 0; k < P2_TILE / 256; k++) {
        int e = base + k * 256 + tid;
        if (e < N_EDGES) {
            int d = dst[e];
            int b = d >> BSHIFT;
            int pos = atomicAdd(&h[b], 1);
            staged[pos] = ((unsigned int)src[e] << BSHIFT) | (unsigned int)(d & (BNODES - 1));
        }
    }
}

// ---------------- pass 3: per-bucket CSR build (+deg, row_start, dinv) ------
__global__ __launch_bounds__(256) void p3_build(unsigned int* __restrict__ ebuf,
                                                const int* __restrict__ bstart,
                                                const int* __restrict__ bcnt,
                                                int* __restrict__ row_start,
                                                int* __restrict__ deg,
                                                float* __restrict__ dinv) {
    __shared__ unsigned int buf[CAP];
    __shared__ int cnt[BNODES];
    __shared__ int cur[BNODES];
    int b = blockIdx.x;
    int tid = threadIdx.x;
    int ebase = bstart[b];
    int ecnt = bcnt[b];
    if (ecnt > CAP) ecnt = CAP;  // statistically impossible; guards LDS
    if (tid < BNODES) cnt[tid] = 0;
    __syncthreads();
    for (int i = tid; i < ecnt; i += 256) {
        unsigned int v = ebuf[ebase + i];
        buf[i] = v;
        atomicAdd(&cnt[v & (BNODES - 1)], 1);
    }
    __syncthreads();
    int c = 0;
    if (tid < BNODES) {
        c = cnt[tid];
        cur[tid] = c;
    }
    __syncthreads();
    for (int off = 1; off < BNODES; off <<= 1) {
        int u = 0;
        if (tid < BNODES && tid >= off) u = cur[tid - off];
        __syncthreads();
        if (tid < BNODES) cur[tid] += u;
        __syncthreads();
    }
    int excl = 0;
    if (tid < BNODES) excl = cur[tid] - c;
    int node = b * BNODES + tid;
    if (tid < BNODES && node < N_NODES) {
        row_start[node] = ebase + excl;
        deg[node] = c;
        dinv[node] = rsqrtf((float)c + 1.0f);  // +1 self-loop
    }
    __syncthreads();
    if (tid < BNODES) cur[tid] = excl;  // local cursor
    __syncthreads();
    for (int i = tid; i < ecnt; i += 256) {
        unsigned int v = buf[i];
        int pos = atomicAdd(&cur[v & (BNODES - 1)], 1);
        ebuf[ebase + pos] = v >> BSHIFT;  // final CSR: src id
    }
}

// ---------------- GEMM1: hs1 = fp16((x @ W1) * dinv[row]) ----------------
__global__ __launch_bounds__(256) void gemm1(const float* __restrict__ x,
                                             const float* __restrict__ W1,
                                             const float* __restrict__ dinv,
                                             __half2* __restrict__ hs1) {
    __shared__ float xs[256 * 33];
    int tid = threadIdx.x;
    int row0 = blockIdx.x * 256;
    int row = row0 + tid;
    float acc[16];
#pragma unroll
    for (int c = 0; c < 16; c++) acc[c] = 0.f;

    float4 r[8];
    // prefetch tile k0=0
#pragma unroll
    for (int l = 0; l < 8; l++) {
        int idx = tid + l * 256;
        int rr = idx >> 3;
        int f4 = idx & 7;
        int gr = row0 + rr;
        r[l] = make_float4(0.f, 0.f, 0.f, 0.f);
        if (gr < N_NODES)
            r[l] = *(const float4*)(x + (size_t)gr * D_IN + f4 * 4);
    }

    for (int k0 = 0; k0 < D_IN; k0 += 32) {
        __syncthreads();
#pragma unroll
        for (int l = 0; l < 8; l++) {
            int idx = tid + l * 256;
            int rr = idx >> 3;
            int f4 = idx & 7;
            int a = rr * 33 + f4 * 4;
            xs[a] = r[l].x; xs[a + 1] = r[l].y; xs[a + 2] = r[l].z; xs[a + 3] = r[l].w;
        }
        __syncthreads();
        if (k0 + 32 < D_IN) {
#pragma unroll
            for (int l = 0; l < 8; l++) {
                int idx = tid + l * 256;
                int rr = idx >> 3;
                int f4 = idx & 7;
                int gr = row0 + rr;
                r[l] = make_float4(0.f, 0.f, 0.f, 0.f);
                if (gr < N_NODES)
                    r[l] = *(const float4*)(x + (size_t)gr * D_IN + (k0 + 32) + f4 * 4);
            }
        }
#pragma unroll
        for (int kk = 0; kk < 32; kk++) {
            float xv = xs[tid * 33 + kk];
            const float* wr = W1 + (k0 + kk) * 16;  // wave-uniform -> s_load
#pragma unroll
            for (int c = 0; c < 16; c++) acc[c] = fmaf(xv, wr[c], acc[c]);
        }
    }
    if (row < N_NODES) {
        float di = dinv[row];
        __half2 p[8];
#pragma unroll
        for (int i = 0; i < 8; i++)
            p[i] = __floats2half2_rn(acc[2 * i] * di, acc[2 * i + 1] * di);
        float4* o = (float4*)(hs1 + (size_t)row * 8);
        o[0] = *(float4*)&p[0];
        o[1] = *(float4*)&p[4];
    }
}

// ---------------- Agg layer 1: wave-per-node pull (8 slots x 8 lanes, fp16) --
// out = di*(sum_s hs1[s] + hs1[node]); then bias+ReLU+@W2, store fp16 *di.
__global__ __launch_bounds__(256) void agg1(const __half2* __restrict__ hs1,
                                            const float* __restrict__ dinv,
                                            const int* __restrict__ row_start,
                                            const int* __restrict__ deg,
                                            const int* __restrict__ csr,
                                            const float* __restrict__ b1,
                                            const float* __restrict__ W2,
                                            __half2* __restrict__ hs3) {
    int tid = threadIdx.x;
    int node = blockIdx.x * 4 + (tid >> 6);
    if (node >= N_NODES) return;
    int lane = tid & 63;
    int slot = lane >> 3;   // 8 edge slots
    int q = lane & 7;       // half2 index within row (features 2q, 2q+1)
    int start = row_start[node];
    int cnt = deg[node];
    float ax = 0.f, ay = 0.f;
    __half2 v0 = __float2half2_rn(0.f), v1 = __float2half2_rn(0.f);
    int t = slot;
    {
        int sA = (t < cnt) ? csr[start + t] : 0;
        int sB = (t + 8 < cnt) ? csr[start + t + 8] : 0;
        if (t < cnt) v0 = hs1[(size_t)sA * 8 + q];
        if (t + 8 < cnt) v1 = hs1[(size_t)sB * 8 + q];
    }
    for (; t < cnt; t += 8) {
        __half2 vC = v0;
        v0 = v1;
        int tn = t + 16;
        if (tn < cnt) {
            int s = csr[start + tn];
            v1 = hs1[(size_t)s * 8 + q];
        } else {
            v1 = __float2half2_rn(0.f);
        }
        float2 f = __half22float2(vC);
        ax += f.x; ay += f.y;
    }
    ax += __shfl_xor(ax, 8);  ay += __shfl_xor(ay, 8);
    ax += __shfl_xor(ax, 16); ay += __shfl_xor(ay, 16);
    ax += __shfl_xor(ax, 32); ay += __shfl_xor(ay, 32);
    float di = dinv[node];
    float2 self = __half22float2(hs1[(size_t)node * 8 + q]);
    float2 bb = ((const float2*)b1)[q];
    float vx = (ax + self.x) * di + bb.x;
    float vy = (ay + self.y) * di + bb.y;
    vx = vx > 0.f ? vx : 0.f;
    vy = vy > 0.f ? vy : 0.f;
    int c0 = q * 2;
    float o0 = 0.f, o1 = 0.f;
#pragma unroll
    for (int j = 0; j < 8; j++) {
        float ujx = __shfl(vx, j, 8);
        float ujy = __shfl(vy, j, 8);
        const float* w0 = W2 + (2 * j) * 16;
        const float* w1 = W2 + (2 * j + 1) * 16;
        o0 = fmaf(ujx, w0[c0], o0);     o0 = fmaf(ujy, w1[c0], o0);
        o1 = fmaf(ujx, w0[c0 + 1], o1); o1 = fmaf(ujy, w1[c0 + 1], o1);
    }
    if (slot == 0) hs3[(size_t)node * 8 + q] = __floats2half2_rn(o0 * di, o1 * di);
}

// ---------------- Agg layer 2: wave-per-node pull + b2 + log_softmax --------
__global__ __launch_bounds__(256) void agg2(const __half2* __restrict__ hs3,
                                            const float* __restrict__ dinv,
                                            const int* __restrict__ row_start,
                                            const int* __restrict__ deg,
                                            const int* __restrict__ csr,
                                            const float* __restrict__ b2,
                                            float* __restrict__ out) {
    int tid = threadIdx.x;
    int node = blockIdx.x * 4 + (tid >> 6);
    if (node >= N_NODES) return;
    int lane = tid & 63;
    int slot = lane >> 3;
    int q = lane & 7;
    int start = row_start[node];
    int cnt = deg[node];
    float ax = 0.f, ay = 0.f;
    __half2 v0 = __float2half2_rn(0.f), v1 = __float2half2_rn(0.f);
    int t = slot;
    {
        int sA = (t < cnt) ? csr[start + t] : 0;
        int sB = (t + 8 < cnt) ? csr[start + t + 8] : 0;
        if (t < cnt) v0 = hs3[(size_t)sA * 8 + q];
        if (t + 8 < cnt) v1 = hs3[(size_t)sB * 8 + q];
    }
    for (; t < cnt; t += 8) {
        __half2 vC = v0;
        v0 = v1;
        int tn = t + 16;
        if (tn < cnt) {
            int s = csr[start + tn];
            v1 = hs3[(size_t)s * 8 + q];
        } else {
            v1 = __float2half2_rn(0.f);
        }
        float2 f = __half22float2(vC);
        ax += f.x; ay += f.y;
    }
    ax += __shfl_xor(ax, 8);  ay += __shfl_xor(ay, 8);
    ax += __shfl_xor(ax, 16); ay += __shfl_xor(ay, 16);
    ax += __shfl_xor(ax, 32); ay += __shfl_xor(ay, 32);
    float di = dinv[node];
    float2 self = __half22float2(hs3[(size_t)node * 8 + q]);
    float2 bb = ((const float2*)b2)[q];
    float lx = (ax + self.x) * di + bb.x;
    float ly = (ay + self.y) * di + bb.y;
    // log_softmax over 16 features (2 per lane x 8 lanes)
    float m = fmaxf(lx, ly);
#pragma unroll
    for (int mask = 1; mask < 8; mask <<= 1)
        m = fmaxf(m, __shfl_xor(m, mask, 8));
    float ex = expf(lx - m), ey = expf(ly - m);
    float s = ex + ey;
#pragma unroll
    for (int mask = 1; mask < 8; mask <<= 1)
        s += __shfl_xor(s, mask, 8);
    float ls = logf(s);
    if (slot == 0) {
        float2 o = make_float2(lx - m - ls, ly - m - ls);
        ((float2*)out)[(size_t)node * 8 + q] = o;
    }
}

extern "C" void kernel_launch(void* const* d_in, const int* in_sizes, int n_in,
                              void* d_out, int out_size, void* d_ws, size_t ws_size,
                              hipStream_t stream) {
    const float* x  = (const float*)d_in[0];
    const float* W1 = (const float*)d_in[1];
    const float* b1 = (const float*)d_in[2];
    const float* W2 = (const float*)d_in[3];
    const float* b2 = (const float*)d_in[4];
    const int*   ei = (const int*)d_in[5];
    const int* src = ei;
    const int* dst = ei + N_EDGES;
    float* out = (float*)d_out;

    // workspace layout (4B elements):
    int* deg       = (int*)d_ws;                  // 100096
    int* row_start = deg + 100096;                // 100096
    float* dinv    = (float*)(row_start + 100096);// 100096
    int* bcnt      = (int*)(dinv + 100096);       // 1024
    int* bstart    = bcnt + 1024;                 // 1024
    int* bcur      = bstart + 1024;               // 1024
    unsigned int* ebuf = (unsigned int*)(bcur + 1024); // 6400000
    __half2* hs1   = (__half2*)(ebuf + N_EDGES);  // 100000*8 half2 = 800000 x 4B
    __half2* hs3   = hs1 + 800000;                // 800000 x 4B

    hipMemsetAsync(bcnt, 0, NB * sizeof(int), stream);
    p1_hist<<<NT1, 256, 0, stream>>>(dst, bcnt);
    p2_scan<<<1, 1024, 0, stream>>>(bcnt, bstart, bcur);
    p2_scatter<<<NT2, 256, 0, stream>>>(src, dst, bcur, ebuf);
    p3_build<<<NB, 256, 0, stream>>>(ebuf, bstart, bcnt, row_start, deg, dinv);
    gemm1<<<(N_NODES + 255) / 256, 256, 0, stream>>>(x, W1, dinv, hs1);
    agg1<<<(N_NODES + 3) / 4, 256, 0, stream>>>(hs1, dinv, row_start, deg, (const int*)ebuf, b1, W2, hs3);
    agg2<<<(N_NODES + 3) / 4, 256, 0, stream>>>(hs3, dinv, row_start, deg, (const int*)ebuf, b2, out);
}

// Round 5
// 611.965 us; speedup vs baseline: 3.2030x; 1.2402x over previous
//
#include <hip/hip_runtime.h>
#include <hip/hip_fp16.h>
#include <math.h>

#define N_NODES 100000
#define N_EDGES 6400000
#define D_IN 512
#define D_HID 16

// ---- bucketed counting-sort parameters ----
#define BSHIFT 7
#define BNODES 128                                   // nodes per bucket
#define NB ((N_NODES + BNODES - 1) / BNODES)         // 782 buckets
#define NBP 800                                      // bhist row pitch
#define P2T 25600                                    // edges per tile (p1/p2)
#define NT2 (N_EDGES / P2T)                          // 250 (exact)
#define CAP 9728                                     // max edges/bucket (mean 8184 + ~17 sigma)

// ---------------- pass 1: per-tile bucket histogram (saved) ----------------
__global__ __launch_bounds__(1024) void p1_hist(const int* __restrict__ dst,
                                                int* __restrict__ bhist,
                                                int* __restrict__ bcnt) {
    __shared__ int h[NB];
    int tid = threadIdx.x;
    if (tid < NB) h[tid] = 0;
    __syncthreads();
    int base = blockIdx.x * P2T;
#pragma unroll
    for (int k = 0; k < P2T / 1024; k++) {
        int e = base + k * 1024 + tid;
        atomicAdd(&h[dst[e] >> BSHIFT], 1);
    }
    __syncthreads();
    if (tid < NB) {
        int c = h[tid];
        bhist[blockIdx.x * NBP + tid] = c;
        if (c) atomicAdd(&bcnt[tid], c);
    }
}

// ---------------- pass 2a: scan bucket counts (1 block) ----------------
__global__ void p2_scan(const int* __restrict__ bcnt, int* __restrict__ bstart,
                        int* __restrict__ bcur) {
    __shared__ int sd[1024];
    int tid = threadIdx.x;  // 1024 threads
    int v = (tid < NB) ? bcnt[tid] : 0;
    sd[tid] = v;
    __syncthreads();
    for (int off = 1; off < 1024; off <<= 1) {
        int u = (tid >= off) ? sd[tid - off] : 0;
        __syncthreads();
        sd[tid] += u;
        __syncthreads();
    }
    if (tid < NB) {
        int ex = sd[tid] - v;
        bstart[tid] = ex;
        bcur[tid] = ex;
    }
}

// ---------------- pass 2b: LDS-sorted multisplit scatter ----------------
// Whole 25600-edge tile counting-sorted in LDS, then dumped as contiguous
// per-bucket runs (coalesced, lines filled in one burst -> no write amp).
__global__ __launch_bounds__(1024) void p2_scatter(const int* __restrict__ src,
                                                   const int* __restrict__ dst,
                                                   const int* __restrict__ bhist,
                                                   int* __restrict__ bcur,
                                                   unsigned int* __restrict__ staged) {
    __shared__ unsigned int sbuf[P2T];   // 100 KB
    __shared__ int loc[NB + 1];
    __shared__ int lcur[NB];
    __shared__ int gbase[NB];
    __shared__ int sd[1024];
    int tid = threadIdx.x;
    int blk = blockIdx.x;
    // load per-tile hist, reserve global runs
    int c = 0;
    if (tid < NB) {
        c = bhist[blk * NBP + tid];
        gbase[tid] = c ? atomicAdd(&bcur[tid], c) : 0;
    }
    sd[tid] = (tid < NB) ? c : 0;
    __syncthreads();
    for (int off = 1; off < 1024; off <<= 1) {
        int u = (tid >= off) ? sd[tid - off] : 0;
        __syncthreads();
        sd[tid] += u;
        __syncthreads();
    }
    if (tid < NB) {
        int ex = sd[tid] - c;
        loc[tid] = ex;
        lcur[tid] = ex;
    }
    if (tid == 0) loc[NB] = P2T;  // sentinel (tile hist sums to P2T exactly)
    __syncthreads();
    // scatter into LDS, sorted by bucket
    int base = blk * P2T;
#pragma unroll
    for (int k = 0; k < P2T / 1024; k++) {
        int e = base + k * 1024 + tid;
        int d = dst[e];
        int b = d >> BSHIFT;
        int pos = atomicAdd(&lcur[b], 1);
        sbuf[pos] = ((unsigned int)src[e] << BSHIFT) | (unsigned int)(d & (BNODES - 1));
    }
    __syncthreads();
    // dump: position j -> bucket via binary search over loc[]
#pragma unroll
    for (int k = 0; k < P2T / 1024; k++) {
        int j = k * 1024 + tid;
        int lo = 0, hi = NB;
        while (hi - lo > 1) {
            int mid = (lo + hi) >> 1;
            if (loc[mid] <= j) lo = mid; else hi = mid;
        }
        staged[gbase[lo] + (j - loc[lo])] = sbuf[j];
    }
}

// ---------------- pass 3: per-bucket CSR build (+deg, row_start, dinv) ------
__global__ __launch_bounds__(512) void p3_build(unsigned int* __restrict__ ebuf,
                                                const int* __restrict__ bstart,
                                                const int* __restrict__ bcnt,
                                                int* __restrict__ row_start,
                                                int* __restrict__ deg,
                                                float* __restrict__ dinv) {
    __shared__ unsigned int buf[CAP];
    __shared__ int cnt[BNODES];
    __shared__ int cur[BNODES];
    int b = blockIdx.x;
    int tid = threadIdx.x;
    int ebase = bstart[b];
    int ecnt = bcnt[b];
    if (ecnt > CAP) ecnt = CAP;  // statistically impossible; guards LDS
    if (tid < BNODES) cnt[tid] = 0;
    __syncthreads();
    for (int i = tid; i < ecnt; i += 512) {
        unsigned int v = ebuf[ebase + i];
        buf[i] = v;
        atomicAdd(&cnt[v & (BNODES - 1)], 1);
    }
    __syncthreads();
    int c = 0;
    if (tid < BNODES) {
        c = cnt[tid];
        cur[tid] = c;
    }
    __syncthreads();
    for (int off = 1; off < BNODES; off <<= 1) {
        int u = 0;
        if (tid < BNODES && tid >= off) u = cur[tid - off];
        __syncthreads();
        if (tid < BNODES) cur[tid] += u;
        __syncthreads();
    }
    int excl = 0;
    if (tid < BNODES) excl = cur[tid] - c;
    int node = b * BNODES + tid;
    if (tid < BNODES && node < N_NODES) {
        row_start[node] = ebase + excl;
        deg[node] = c;
        dinv[node] = rsqrtf((float)c + 1.0f);  // +1 self-loop
    }
    __syncthreads();
    if (tid < BNODES) cur[tid] = excl;  // local cursor
    __syncthreads();
    for (int i = tid; i < ecnt; i += 512) {
        unsigned int v = buf[i];
        int pos = atomicAdd(&cur[v & (BNODES - 1)], 1);
        ebuf[ebase + pos] = v >> BSHIFT;  // final CSR: src id
    }
}

// ---------------- GEMM1: hs1 = fp16((x @ W1) * dinv[row]) ----------------
__global__ __launch_bounds__(256) void gemm1(const float* __restrict__ x,
                                             const float* __restrict__ W1,
                                             const float* __restrict__ dinv,
                                             __half2* __restrict__ hs1) {
    __shared__ float xs[256 * 33];
    int tid = threadIdx.x;
    int row0 = blockIdx.x * 256;
    int row = row0 + tid;
    float acc[16];
#pragma unroll
    for (int c = 0; c < 16; c++) acc[c] = 0.f;

    float4 r[8];
#pragma unroll
    for (int l = 0; l < 8; l++) {
        int idx = tid + l * 256;
        int rr = idx >> 3;
        int f4 = idx & 7;
        int gr = row0 + rr;
        r[l] = make_float4(0.f, 0.f, 0.f, 0.f);
        if (gr < N_NODES)
            r[l] = *(const float4*)(x + (size_t)gr * D_IN + f4 * 4);
    }

    for (int k0 = 0; k0 < D_IN; k0 += 32) {
        __syncthreads();
#pragma unroll
        for (int l = 0; l < 8; l++) {
            int idx = tid + l * 256;
            int rr = idx >> 3;
            int f4 = idx & 7;
            int a = rr * 33 + f4 * 4;
            xs[a] = r[l].x; xs[a + 1] = r[l].y; xs[a + 2] = r[l].z; xs[a + 3] = r[l].w;
        }
        __syncthreads();
        if (k0 + 32 < D_IN) {
#pragma unroll
            for (int l = 0; l < 8; l++) {
                int idx = tid + l * 256;
                int rr = idx >> 3;
                int f4 = idx & 7;
                int gr = row0 + rr;
                r[l] = make_float4(0.f, 0.f, 0.f, 0.f);
                if (gr < N_NODES)
                    r[l] = *(const float4*)(x + (size_t)gr * D_IN + (k0 + 32) + f4 * 4);
            }
        }
#pragma unroll
        for (int kk = 0; kk < 32; kk++) {
            float xv = xs[tid * 33 + kk];
            const float* wr = W1 + (k0 + kk) * 16;  // wave-uniform -> s_load
#pragma unroll
            for (int c = 0; c < 16; c++) acc[c] = fmaf(xv, wr[c], acc[c]);
        }
    }
    if (row < N_NODES) {
        float di = dinv[row];
        __half2 p[8];
#pragma unroll
        for (int i = 0; i < 8; i++)
            p[i] = __floats2half2_rn(acc[2 * i] * di, acc[2 * i + 1] * di);
        float4* o = (float4*)(hs1 + (size_t)row * 8);
        o[0] = *(float4*)&p[0];
        o[1] = *(float4*)&p[4];
    }
}

// ---------------- Agg layer 1: wave-per-node pull (8 slots x 8 lanes, fp16) --
__global__ __launch_bounds__(256) void agg1(const __half2* __restrict__ hs1,
                                            const float* __restrict__ dinv,
                                            const int* __restrict__ row_start,
                                            const int* __restrict__ deg,
                                            const int* __restrict__ csr,
                                            const float* __restrict__ b1,
                                            const float* __restrict__ W2,
                                            __half2* __restrict__ hs3) {
    int tid = threadIdx.x;
    int node = blockIdx.x * 4 + (tid >> 6);
    if (node >= N_NODES) return;
    int lane = tid & 63;
    int slot = lane >> 3;   // 8 edge slots
    int q = lane & 7;       // half2 index within row (features 2q, 2q+1)
    int start = row_start[node];
    int cnt = deg[node];
    float ax = 0.f, ay = 0.f;
    __half2 v0 = __float2half2_rn(0.f), v1 = __float2half2_rn(0.f);
    int t = slot;
    {
        int sA = (t < cnt) ? csr[start + t] : 0;
        int sB = (t + 8 < cnt) ? csr[start + t + 8] : 0;
        if (t < cnt) v0 = hs1[(size_t)sA * 8 + q];
        if (t + 8 < cnt) v1 = hs1[(size_t)sB * 8 + q];
    }
    for (; t < cnt; t += 8) {
        __half2 vC = v0;
        v0 = v1;
        int tn = t + 16;
        if (tn < cnt) {
            int s = csr[start + tn];
            v1 = hs1[(size_t)s * 8 + q];
        } else {
            v1 = __float2half2_rn(0.f);
        }
        float2 f = __half22float2(vC);
        ax += f.x; ay += f.y;
    }
    ax += __shfl_xor(ax, 8);  ay += __shfl_xor(ay, 8);
    ax += __shfl_xor(ax, 16); ay += __shfl_xor(ay, 16);
    ax += __shfl_xor(ax, 32); ay += __shfl_xor(ay, 32);
    float di = dinv[node];
    float2 self = __half22float2(hs1[(size_t)node * 8 + q]);
    float2 bb = ((const float2*)b1)[q];
    float vx = (ax + self.x) * di + bb.x;
    float vy = (ay + self.y) * di + bb.y;
    vx = vx > 0.f ? vx : 0.f;
    vy = vy > 0.f ? vy : 0.f;
    int c0 = q * 2;
    float o0 = 0.f, o1 = 0.f;
#pragma unroll
    for (int j = 0; j < 8; j++) {
        float ujx = __shfl(vx, j, 8);
        float ujy = __shfl(vy, j, 8);
        const float* w0 = W2 + (2 * j) * 16;
        const float* w1 = W2 + (2 * j + 1) * 16;
        o0 = fmaf(ujx, w0[c0], o0);     o0 = fmaf(ujy, w1[c0], o0);
        o1 = fmaf(ujx, w0[c0 + 1], o1); o1 = fmaf(ujy, w1[c0 + 1], o1);
    }
    if (slot == 0) hs3[(size_t)node * 8 + q] = __floats2half2_rn(o0 * di, o1 * di);
}

// ---------------- Agg layer 2: wave-per-node pull + b2 + log_softmax --------
__global__ __launch_bounds__(256) void agg2(const __half2* __restrict__ hs3,
                                            const float* __restrict__ dinv,
                                            const int* __restrict__ row_start,
                                            const int* __restrict__ deg,
                                            const int* __restrict__ csr,
                                            const float* __restrict__ b2,
                                            float* __restrict__ out) {
    int tid = threadIdx.x;
    int node = blockIdx.x * 4 + (tid >> 6);
    if (node >= N_NODES) return;
    int lane = tid & 63;
    int slot = lane >> 3;
    int q = lane & 7;
    int start = row_start[node];
    int cnt = deg[node];
    float ax = 0.f, ay = 0.f;
    __half2 v0 = __float2half2_rn(0.f), v1 = __float2half2_rn(0.f);
    int t = slot;
    {
        int sA = (t < cnt) ? csr[start + t] : 0;
        int sB = (t + 8 < cnt) ? csr[start + t + 8] : 0;
        if (t < cnt) v0 = hs3[(size_t)sA * 8 + q];
        if (t + 8 < cnt) v1 = hs3[(size_t)sB * 8 + q];
    }
    for (; t < cnt; t += 8) {
        __half2 vC = v0;
        v0 = v1;
        int tn = t + 16;
        if (tn < cnt) {
            int s = csr[start + tn];
            v1 = hs3[(size_t)s * 8 + q];
        } else {
            v1 = __float2half2_rn(0.f);
        }
        float2 f = __half22float2(vC);
        ax += f.x; ay += f.y;
    }
    ax += __shfl_xor(ax, 8);  ay += __shfl_xor(ay, 8);
    ax += __shfl_xor(ax, 16); ay += __shfl_xor(ay, 16);
    ax += __shfl_xor(ax, 32); ay += __shfl_xor(ay, 32);
    float di = dinv[node];
    float2 self = __half22float2(hs3[(size_t)node * 8 + q]);
    float2 bb = ((const float2*)b2)[q];
    float lx = (ax + self.x) * di + bb.x;
    float ly = (ay + self.y) * di + bb.y;
    float m = fmaxf(lx, ly);
#pragma unroll
    for (int mask = 1; mask < 8; mask <<= 1)
        m = fmaxf(m, __shfl_xor(m, mask, 8));
    float ex = expf(lx - m), ey = expf(ly - m);
    float s = ex + ey;
#pragma unroll
    for (int mask = 1; mask < 8; mask <<= 1)
        s += __shfl_xor(s, mask, 8);
    float ls = logf(s);
    if (slot == 0) {
        float2 o = make_float2(lx - m - ls, ly - m - ls);
        ((float2*)out)[(size_t)node * 8 + q] = o;
    }
}

extern "C" void kernel_launch(void* const* d_in, const int* in_sizes, int n_in,
                              void* d_out, int out_size, void* d_ws, size_t ws_size,
                              hipStream_t stream) {
    const float* x  = (const float*)d_in[0];
    const float* W1 = (const float*)d_in[1];
    const float* b1 = (const float*)d_in[2];
    const float* W2 = (const float*)d_in[3];
    const float* b2 = (const float*)d_in[4];
    const int*   ei = (const int*)d_in[5];
    const int* src = ei;
    const int* dst = ei + N_EDGES;
    float* out = (float*)d_out;

    // workspace layout (4B elements):
    int* deg       = (int*)d_ws;                  // 100096
    int* row_start = deg + 100096;                // 100096
    float* dinv    = (float*)(row_start + 100096);// 100096
    int* bcnt      = (int*)(dinv + 100096);       // 1024
    int* bstart    = bcnt + 1024;                 // 1024
    int* bcur      = bstart + 1024;               // 1024
    int* bhist     = bcur + 1024;                 // 250*800 = 200000
    unsigned int* ebuf = (unsigned int*)(bhist + 200000); // 6400000
    __half2* hs1   = (__half2*)(ebuf + N_EDGES);  // 800000 x 4B
    __half2* hs3   = hs1 + 800000;                // 800000 x 4B

    hipMemsetAsync(bcnt, 0, NB * sizeof(int), stream);
    p1_hist<<<NT2, 1024, 0, stream>>>(dst, bhist, bcnt);
    p2_scan<<<1, 1024, 0, stream>>>(bcnt, bstart, bcur);
    p2_scatter<<<NT2, 1024, 0, stream>>>(src, dst, bhist, bcur, ebuf);
    p3_build<<<NB, 512, 0, stream>>>(ebuf, bstart, bcnt, row_start, deg, dinv);
    gemm1<<<(N_NODES + 255) / 256, 256, 0, stream>>>(x, W1, dinv, hs1);
    agg1<<<(N_NODES + 3) / 4, 256, 0, stream>>>(hs1, dinv, row_start, deg, (const int*)ebuf, b1, W2, hs3);
    agg2<<<(N_NODES + 3) / 4, 256, 0, stream>>>(hs3, dinv, row_start, deg, (const int*)ebuf, b2, out);
}